// Round 9
// baseline (799.847 us; speedup 1.0000x reference)
//
#include <hip/hip_runtime.h>
#include <cstdint>
#include <cstddef>

typedef __bf16 bf16x8 __attribute__((ext_vector_type(8)));
typedef __bf16 bf16x4 __attribute__((ext_vector_type(4)));
typedef float  f32x4  __attribute__((ext_vector_type(4)));

#define MFMA16(a,b,c) __builtin_amdgcn_mfma_f32_16x16x32_bf16((a),(b),(c),0,0,0)

#define BAR_LGKM() __asm__ volatile("s_waitcnt lgkmcnt(0)\n\ts_barrier" ::: "memory")
#define BAR_FULL() __asm__ volatile("s_waitcnt vmcnt(0) lgkmcnt(0)\n\ts_barrier" ::: "memory")

#define L2E  1.4426950408889634f   // log2(e)
#define L2E2 2.8853900817779268f   // 2*log2(e)

// Problem: B=256, T=512, D=H=128, 3H=384. x/out batch stride = 65536 elems.
//
// Round-9 = round-8 THIN-BATCH WIDE-GRID with the cross-XCD protocol fixed.
// Round-8's absmax=0.62 diagnosis: rounds 0-7 paired blocks (p, p+16) ->
// same XCD under bid%8 dispatch, so relaxed flags + nt stores worked by
// placement luck. Round-8's (2p, 2p+1) pairing crossed non-coherent L2s.
// Fixes:
//  1) same-XCD pairing: layer=(bid>>3)&1, pair=(bid&7)|((bid>>4)<<3)
//     (producer 16q+r, consumer 16q+8+r, both XCD r under bid%8).
//  2) RELEASE on flag publish / ACQUIRE on consumer poll (agent scope) ->
//     correct regardless of XCD placement (Guideline 16).
//  3) A-frag loads unmasked: lanes l15 not in {0,8} read the duplicate of
//     LDS row (l15>>3) -- same-address LDS broadcast (free); duplicate
//     C rows are never stored. (Removes the divergent persistent-register
//     pattern, a second failure candidate.)
// 256 blocks (all CUs): 128 pairs x 2 batch rows at MFMA tile rows {0,8}.
// Per-block MFMA count unchanged (fixed by gates x K); epilogue VALU,
// staging, stores, LDS traffic all shrink ~8x chip-wide-constant.
// Math identical to round-5 (same accumulation order): xp carry in regs
// (split W/U, C-init fusion), exp2-prescaled weights, pinned frags.

// ---------------------------------------------------------------------------
// prep_frags: stacked-weight B-frags, K=256 ([W(128) ; U(128)]), + flag init.
// Frag layout (16x16x32): B[k][n], n = lane&15, k = kt*32 + (lane>>4)*8 + j.
// Elem offset = ((ct*8+kt)*64 + lane)*8 + j, ct 0..23 (z:0-7,r:8-15,h:16-23),
// kt 0..7 (kt<4 -> W rows k, kt>=4 -> U rows k-128). Per layer: 98304 bf16.
// Values pre-scaled: L2E for z/r cols (ct<16), L2E2 for h cols (ct>=16).
// ---------------------------------------------------------------------------
__global__ void prep_frags(const float* __restrict__ W0, const float* __restrict__ U0,
                           const float* __restrict__ W1, const float* __restrict__ U1,
                           __bf16* __restrict__ frags, int* __restrict__ flags)
{
    if (blockIdx.x == 0 && threadIdx.x < 128) flags[threadIdx.x * 16] = 0;
    int id = blockIdx.x * 512 + threadIdx.x;      // 0..24575
    int layer = id / 12288;
    int r     = id % 12288;                       // (ct*8+kt)*64 + lane
    int lane = r & 63;
    int ctkt = r >> 6;                            // 0..191
    int kt = ctkt & 7;
    int ct = ctkt >> 3;
    const float* Wsrc = layer ? W1 : W0;
    const float* Usrc = layer ? U1 : U0;
    int n  = ct * 16 + (lane & 15);
    int k0 = kt * 32 + (lane >> 4) * 8;           // never straddles 128
    const float* src = (k0 < 128) ? (Wsrc + (size_t)k0 * 384)
                                  : (Usrc + (size_t)(k0 - 128) * 384);
    const float s = (ct < 16) ? L2E : L2E2;       // z,r vs h columns
    __bf16* dst = frags + (size_t)layer * 98304 + (size_t)r * 8;
#pragma unroll
    for (int j = 0; j < 8; j++)
        dst[j] = (__bf16)(src[(size_t)j * 384 + n] * s);
}

// ---------------------------------------------------------------------------
// gru_pipe: per block 2 batch rows (tile rows 0,8 <-> LDS rows 0,1),
// 512 threads (8 waves, 2/SIMD). Wave w owns hidden col j=16w+l15 for all
// gates. Per step t:
//   rec: az/ar/ahh = h_{t-1}.U with C-init = xp carry (z,r) / 0 (h)
//   xp:  xp_{t+2} = x_{t+2}.W  (independent, drains under the epilogue)
// Epilogue: r=0 only (valid output rows: quad 0 -> batch row 2p, quad 2 ->
// row 2p+1); stores masked to !(quad&1). Wave 0 does all x staging and
// (layer 1) flag polling. Producer publishes flag=t every 4th step after a
// FULL drain + RELEASE: flag F asserts h0 steps 0..F-1 are in HBM/visible.
// Consumer raises `known` with ACQUIRE loads; loads h0_{t+4} at step t
// gated on known >= t+5. h0 may alias out (small-ws fallback): consumer
// reads slot t+4 strictly before overwriting slot t. No __restrict__ on
// x/h0/out.
// ---------------------------------------------------------------------------
__global__ __launch_bounds__(512, 2) void gru_pipe(
    const float* x, const __bf16* __restrict__ frags,
    const float* __restrict__ b0, const float* __restrict__ b1,
    float* h0, float* out, int* flags)
{
    __shared__ __align__(16) __bf16 xb[2][256];    // x tiles: 2 rows x 128
    __shared__ __align__(16) __bf16 hb[2][256];    // h ring:  2 rows x 128

    const int tid  = threadIdx.x;
    const int wave = tid >> 6, lane = tid & 63;
    const int l15  = lane & 15, quad = lane >> 4;
    const int bid   = blockIdx.x;
    const int layer = (bid >> 3) & 1;              // same-XCD pairing
    const int pair  = (bid & 7) | ((bid >> 4) << 3);   // 0..127
    const int B0 = pair * 2;
    int* const flagp = flags + pair * 16;          // one 64B line per pair

    const __bf16* Bf  = frags + (size_t)layer * 98304;
    const float* bias = layer ? b1 : b0;
    const float* xin  = layer ? h0 : x;
    float*       hout = layer ? out : h0;

    // persistent B-frags: W part (kt 0..3) and U part (kt 4..7), pinned so
    // the loads cannot be sunk into the t-loop (round-4 lesson).
    bf16x8 bw[3][4], bu[3][4];
#pragma unroll
    for (int g = 0; g < 3; g++) {
        int ct = 8 * g + wave;
#pragma unroll
        for (int kt = 0; kt < 4; kt++) {
            bw[g][kt] = *(const bf16x8*)(Bf + (size_t)((ct * 8 + kt) * 64 + lane) * 8);
            bu[g][kt] = *(const bf16x8*)(Bf + (size_t)((ct * 8 + kt + 4) * 64 + lane) * 8);
            __asm__ volatile("" : "+v"(bw[g][kt]));
            __asm__ volatile("" : "+v"(bu[g][kt]));
        }
    }

    const int j = wave * 16 + l15;
    const float bz  = (bias[j]       + bias[384 + j]) * L2E;
    const float br  = (bias[128 + j] + bias[512 + j]) * L2E;
    const float bxh = bias[256 + j] * L2E2;
    const float brh = bias[640 + j] * L2E2;

    // A-frag byte base: LDS row (l15>>3), k-slice quad*8; +kt*64 bytes.
    // Lanes with l15 not in {0,8} read duplicates (same-address broadcast).
    const int aoff = (l15 >> 3) * 256 + quad * 16;

    // h-write (valid lanes quad 0,2): LDS row quad>>1, col j
    const int  hwb = (quad >> 1) * 256 + j * 2;
    const bool orow_ok = (quad & 1) == 0;
    const size_t obase = (size_t)(B0 + (quad >> 1)) * 65536 + j;

    // staging map (wave 0 only): 64 threads = 2 rows x 32 cols x f32x4
    const int sr = (tid >> 5) & 1;
    const float* px = xin + (size_t)(B0 + sr) * 65536 + (tid & 31) * 4;
    const int sb = sr * 256 + (tid & 31) * 8;      // byte offset in xb buf

    int known = 0;

#define LOADX(p) (layer ? __builtin_nontemporal_load((const f32x4*)(p)) \
                        : *(const f32x4*)(p))
#define PACKST(buf, v) do { bf16x4 hv_;                                  \
        hv_.x = (__bf16)(v)[0]; hv_.y = (__bf16)(v)[1];                  \
        hv_.z = (__bf16)(v)[2]; hv_.w = (__bf16)(v)[3];                  \
        *(bf16x4*)((char*)&(buf)[0] + sb) = hv_; } while (0)
#define POLL_ACQ(need_) do {                                             \
        while (known < (need_)) {                                        \
            __builtin_amdgcn_s_sleep(4);                                 \
            known = __hip_atomic_load(flagp, __ATOMIC_ACQUIRE,           \
                                      __HIP_MEMORY_SCOPE_AGENT);         \
        } } while (0)

    const f32x4 zv = {0.f, 0.f, 0.f, 0.f};
    f32x4 vc = zv;

    // ---- prologue ----
    if (tid < 64) {
        if (layer) POLL_ACQ(4);           // covers h0 slots 0..3
        f32x4 v0 = LOADX(px);
        f32x4 v1 = LOADX(px + 128);
        PACKST(xb[0], v0);
        PACKST(xb[1], v1);
        ((uint64_t*)&hb[0][0])[tid] = 0ull;        // h_{-1}: 2 rows = 512 B
    }
    __syncthreads();

    f32x4 xpzE = zv, xprE = zv, xphE = zv;         // xp_0 (even set)
    f32x4 xpzO = zv, xprO = zv, xphO = zv;         // xp_1 (odd set)
    {
        bf16x8 Ax0 = *(const bf16x8*)((const char*)&xb[0][0] + aoff);
        bf16x8 Ax1 = *(const bf16x8*)((const char*)&xb[0][0] + aoff + 64);
        bf16x8 Ax2 = *(const bf16x8*)((const char*)&xb[0][0] + aoff + 128);
        bf16x8 Ax3 = *(const bf16x8*)((const char*)&xb[0][0] + aoff + 192);
        xpzE = MFMA16(Ax0, bw[0][0], xpzE); xprE = MFMA16(Ax0, bw[1][0], xprE); xphE = MFMA16(Ax0, bw[2][0], xphE);
        xpzE = MFMA16(Ax1, bw[0][1], xpzE); xprE = MFMA16(Ax1, bw[1][1], xprE); xphE = MFMA16(Ax1, bw[2][1], xphE);
        xpzE = MFMA16(Ax2, bw[0][2], xpzE); xprE = MFMA16(Ax2, bw[1][2], xprE); xphE = MFMA16(Ax2, bw[2][2], xphE);
        xpzE = MFMA16(Ax3, bw[0][3], xpzE); xprE = MFMA16(Ax3, bw[1][3], xprE); xphE = MFMA16(Ax3, bw[2][3], xphE);
    }
    {
        bf16x8 Ax0 = *(const bf16x8*)((const char*)&xb[1][0] + aoff);
        bf16x8 Ax1 = *(const bf16x8*)((const char*)&xb[1][0] + aoff + 64);
        bf16x8 Ax2 = *(const bf16x8*)((const char*)&xb[1][0] + aoff + 128);
        bf16x8 Ax3 = *(const bf16x8*)((const char*)&xb[1][0] + aoff + 192);
        xpzO = MFMA16(Ax0, bw[0][0], xpzO); xprO = MFMA16(Ax0, bw[1][0], xprO); xphO = MFMA16(Ax0, bw[2][0], xphO);
        xpzO = MFMA16(Ax1, bw[0][1], xpzO); xprO = MFMA16(Ax1, bw[1][1], xprO); xphO = MFMA16(Ax1, bw[2][1], xphO);
        xpzO = MFMA16(Ax2, bw[0][2], xpzO); xprO = MFMA16(Ax2, bw[1][2], xprO); xphO = MFMA16(Ax2, bw[2][2], xphO);
        xpzO = MFMA16(Ax3, bw[0][3], xpzO); xprO = MFMA16(Ax3, bw[1][3], xprO); xphO = MFMA16(Ax3, bw[2][3], xphO);
    }
    __syncthreads();                                // all reads of xb[0] done
    if (tid < 64) {
        f32x4 v2 = LOADX(px + 256);                 // x_2 -> slot 0
        PACKST(xb[0], v2);
        vc = LOADX(px + 384);                       // x_3 (staged at t=0)
    }
    float hold0 = 0.f;
    __syncthreads();

    // Loop invariant at step t: hb[t&1] = h_{t-1}; xb[t&1] = x_{t+2};
    // xp carry (parity set) = xp_t; vc = x_{t+3} (wave 0).
#define GRU_BODY(T, S, xpz, xpr, xph)                                         \
    {                                                                         \
        const int t_ = (T);                                                   \
        f32x4 vn = zv;                                                        \
        if (tid < 64) {                                                       \
            if (layer) {                            /* gate h0_{t+4} load */  \
                int need = t_ + 5; if (need > 512) need = 512;                \
                POLL_ACQ(need);                                               \
            }                                                                 \
            int t4_ = t_ + 4; if (t4_ > 511) t4_ = 511;                       \
            vn = LOADX(px + (size_t)t4_ * 128);                               \
        }                                                                     \
        bf16x8 Ah0 = *(const bf16x8*)((const char*)&hb[S][0] + aoff);         \
        bf16x8 Ah1 = *(const bf16x8*)((const char*)&hb[S][0] + aoff + 64);    \
        bf16x8 Ah2 = *(const bf16x8*)((const char*)&hb[S][0] + aoff + 128);   \
        bf16x8 Ah3 = *(const bf16x8*)((const char*)&hb[S][0] + aoff + 192);   \
        __builtin_amdgcn_s_setprio(1);                                        \
        f32x4 az  = MFMA16(Ah0, bu[0][0], xpz);                               \
        f32x4 ar  = MFMA16(Ah0, bu[1][0], xpr);                               \
        f32x4 ahh = MFMA16(Ah0, bu[2][0], zv);                                \
        az = MFMA16(Ah1, bu[0][1], az); ar = MFMA16(Ah1, bu[1][1], ar);       \
        ahh = MFMA16(Ah1, bu[2][1], ahh);                                     \
        az = MFMA16(Ah2, bu[0][2], az); ar = MFMA16(Ah2, bu[1][2], ar);       \
        ahh = MFMA16(Ah2, bu[2][2], ahh);                                     \
        az = MFMA16(Ah3, bu[0][3], az); ar = MFMA16(Ah3, bu[1][3], ar);       \
        ahh = MFMA16(Ah3, bu[2][3], ahh);                                     \
        bf16x8 Ax0 = *(const bf16x8*)((const char*)&xb[S][0] + aoff);         \
        bf16x8 Ax1 = *(const bf16x8*)((const char*)&xb[S][0] + aoff + 64);    \
        bf16x8 Ax2 = *(const bf16x8*)((const char*)&xb[S][0] + aoff + 128);   \
        bf16x8 Ax3 = *(const bf16x8*)((const char*)&xb[S][0] + aoff + 192);   \
        f32x4 xhc = xph;                          /* xp_t h-part for epi */   \
        xpz = MFMA16(Ax0, bw[0][0], zv);                                      \
        xpr = MFMA16(Ax0, bw[1][0], zv);                                      \
        xph = MFMA16(Ax0, bw[2][0], zv);                                      \
        xpz = MFMA16(Ax1, bw[0][1], xpz); xpr = MFMA16(Ax1, bw[1][1], xpr);   \
        xph = MFMA16(Ax1, bw[2][1], xph);                                     \
        xpz = MFMA16(Ax2, bw[0][2], xpz); xpr = MFMA16(Ax2, bw[1][2], xpr);   \
        xph = MFMA16(Ax2, bw[2][2], xph);                                     \
        xpz = MFMA16(Ax3, bw[0][3], xpz); xpr = MFMA16(Ax3, bw[1][3], xpr);   \
        xph = MFMA16(Ax3, bw[2][3], xph);                                     \
        __builtin_amdgcn_s_setprio(0);                                        \
        /* epilogue, r=0 only (valid rows live in quads 0,2) */               \
        float z  = __builtin_amdgcn_rcpf(                                     \
                       1.f + __builtin_amdgcn_exp2f(-(az[0] + bz)));          \
        float rg = __builtin_amdgcn_rcpf(                                     \
                       1.f + __builtin_amdgcn_exp2f(-(ar[0] + br)));          \
        float hp = (xhc[0] + bxh) + rg * (ahh[0] + brh);                      \
        float e2 = __builtin_amdgcn_exp2f(hp);                                \
        float th = 1.f - 2.f * __builtin_amdgcn_rcpf(e2 + 1.f);               \
        float hn = th + z * (hold0 - th);                                     \
        hold0 = hn;                                                           \
        if (tid < 64) PACKST(xb[(S) ^ 1], vc);      /* stage x_{t+3} */       \
        if (orow_ok)                                                          \
            *(__bf16*)((char*)&hb[(S) ^ 1][0] + hwb) = (__bf16)hn;            \
        if (layer == 0 && (t_ & 3) == 3) {                                    \
            BAR_FULL();               /* h0 stores of steps <= t-1 in HBM */  \
            if (tid == 0)                                                     \
                __hip_atomic_store(flagp, t_, __ATOMIC_RELEASE,               \
                                   __HIP_MEMORY_SCOPE_AGENT);                 \
        } else {                                                              \
            BAR_LGKM();                                                       \
        }                                                                     \
        if (orow_ok) {                                                        \
            if (layer == 0)                                                   \
                __builtin_nontemporal_store(hn,                               \
                    hout + obase + (size_t)t_ * 128);                         \
            else                                                              \
                hout[obase + (size_t)t_ * 128] = hn;                          \
        }                                                                     \
        vc = vn;                                                              \
    }

    for (int it = 0; it < 256; ++it) {
        GRU_BODY(2 * it,     0, xpzE, xprE, xphE);
        GRU_BODY(2 * it + 1, 1, xpzO, xprO, xphO);
    }
#undef GRU_BODY
#undef POLL_ACQ
#undef PACKST
#undef LOADX

    if (layer == 0) {
        BAR_FULL();        // drain final h0 stores (incl. step 511)
        if (tid == 0)
            __hip_atomic_store(flagp, 512, __ATOMIC_RELEASE,
                               __HIP_MEMORY_SCOPE_AGENT);
    }
}

// ---------------------------------------------------------------------------
extern "C" void kernel_launch(void* const* d_in, const int* in_sizes, int n_in,
                              void* d_out, int out_size, void* d_ws, size_t ws_size,
                              hipStream_t stream)
{
    const float* x  = (const float*)d_in[0];
    const float* W0 = (const float*)d_in[1];
    const float* U0 = (const float*)d_in[2];
    const float* b0 = (const float*)d_in[3];
    const float* W1 = (const float*)d_in[4];
    const float* U1 = (const float*)d_in[5];
    const float* b1 = (const float*)d_in[6];
    float* out = (float*)d_out;

    char* ws = (char*)d_ws;
    __bf16* frags = (__bf16*)ws;                 // 2 * 98304 bf16 = 393,216 B
    int*    flags = (int*)(ws + 393216);         // 128 pairs x 64 B = 8192 B
    // h0 at ws + 448 KiB if it fits, else alias d_out (pipeline-safe: consumer
    // reads slot t+4 strictly before overwriting slot t).
    float* h0;
    const size_t need = 458752 + 67108864;
    if (ws_size >= need) h0 = (float*)(ws + 458752);
    else                 h0 = out;

    prep_frags<<<48, 512, 0, stream>>>(W0, U0, W1, U1, frags, flags);
    gru_pipe<<<256, 512, 0, stream>>>(x, frags, b0, b1, h0, out, flags);
}

// Round 10
// 575.112 us; speedup vs baseline: 1.3908x; 1.3908x over previous
//
#include <hip/hip_runtime.h>
#include <cstdint>
#include <cstddef>

typedef __bf16 bf16x8 __attribute__((ext_vector_type(8)));
typedef __bf16 bf16x4 __attribute__((ext_vector_type(4)));
typedef float  f32x4  __attribute__((ext_vector_type(4)));

#define MFMA16(a,b,c) __builtin_amdgcn_mfma_f32_16x16x32_bf16((a),(b),(c),0,0,0)

// LDS-only barrier: per-step double-buffer handoff needs lgkmcnt(0) only.
// Global stores drained explicitly at publish points (BAR_FULL).
#define BAR_LGKM() __asm__ volatile("s_waitcnt lgkmcnt(0)\n\ts_barrier" ::: "memory")
#define BAR_FULL() __asm__ volatile("s_waitcnt vmcnt(0) lgkmcnt(0)\n\ts_barrier" ::: "memory")

#define L2E  1.4426950408889634f   // log2(e)
#define L2E2 2.8853900817779268f   // 2*log2(e)

// Problem: B=256, T=512, D=H=128, 3H=384. x/out batch stride = 65536 elems.
// 32 blocks: 0..15 layer 0 (producer), 16..31 layer 1 (consumer, lagged).
// h0 crosses XCDs via nt stores/loads + per-pair agent-scope flags.
// (Round-9 lesson: thin-batch/wide-grid regresses — per-block MFMA count is
// row-independent, and cross-XCD release/acquire fences cost ~1700 cyc/step.
// This kernel is the round-5 champion structure.)
//
// Round-10 changes (champion + 2 levers):
//  1) T19 sched_group_barrier ladder per step: {8 DS_READ} -> {12 MFMA rec
//     chain} -> 12 x {1 MFMA (xp) + 6 VALU (epilogue)}. Round-5 counters
//     showed VALUBusy+MfmaUtil ~82% per active CU with ~zero overlap (pipes
//     sum-serialized): the epilogue was emitted after the whole MFMA
//     cluster. The ladder drains the 12 independent xp MFMAs through the
//     ~72 epilogue VALU ops.
//  2) Poll decimation: layer-1 reads the remote flag only every 4th step
//     (need=t+8), removing 3/4 of cross-XCD flag loads from the consumer
//     critical path.

// ---------------------------------------------------------------------------
// prep_frags: stacked-weight B-frags, K=256 ([W(128) ; U(128)]), + flag init.
// Frag layout (16x16x32): B[k][n], n = lane&15, k = kt*32 + (lane>>4)*8 + j.
// Elem offset = ((ct*8+kt)*64 + lane)*8 + j, ct 0..23 (z:0-7,r:8-15,h:16-23),
// kt 0..7 (kt<4 -> W rows k, kt>=4 -> U rows k-128). Per layer: 98304 bf16.
// Values pre-scaled: L2E for z/r cols (ct<16), L2E2 for h cols (ct>=16).
// ---------------------------------------------------------------------------
__global__ void prep_frags(const float* __restrict__ W0, const float* __restrict__ U0,
                           const float* __restrict__ W1, const float* __restrict__ U1,
                           __bf16* __restrict__ frags, int* __restrict__ flags)
{
    if (blockIdx.x == 0 && threadIdx.x < 16) flags[threadIdx.x * 16] = 0;
    int id = blockIdx.x * 512 + threadIdx.x;      // 0..24575
    int layer = id / 12288;
    int r     = id % 12288;                       // (ct*8+kt)*64 + lane
    int lane = r & 63;
    int ctkt = r >> 6;                            // 0..191
    int kt = ctkt & 7;
    int ct = ctkt >> 3;
    const float* Wsrc = layer ? W1 : W0;
    const float* Usrc = layer ? U1 : U0;
    int n  = ct * 16 + (lane & 15);
    int k0 = kt * 32 + (lane >> 4) * 8;           // never straddles 128
    const float* src = (k0 < 128) ? (Wsrc + (size_t)k0 * 384)
                                  : (Usrc + (size_t)(k0 - 128) * 384);
    const float s = (ct < 16) ? L2E : L2E2;       // z,r vs h columns
    __bf16* dst = frags + (size_t)layer * 98304 + (size_t)r * 8;
#pragma unroll
    for (int j = 0; j < 8; j++)
        dst[j] = (__bf16)(src[(size_t)j * 384 + n] * s);
}

// ---------------------------------------------------------------------------
// gru_pipe: per block 16 batch rows, 512 threads (8 waves, 2/SIMD). Wave w
// owns hidden col j=16w+l15 for all gates. Per step t:
//   rec: az/ar (C-init = xp carry) += h_{t-1}.U ; ahh = h-gate rec part
//   indep: xp_{t+2} = x_{t+2}.W  (interleaved with the epilogue via SGB)
// Producer publishes flag=t every 4th step after a FULL drain: flag F
// asserts h0 steps 0..F-1 are in HBM. Consumer polls every 4th step for
// flag >= t+8 (covers prefetch loads t..t+3 -> slots t+4..t+7); prologue
// gates on flag >= 8. h0 may alias out (small-ws fallback): consumer reads
// slot t+4 strictly before overwriting slot t. No __restrict__ on x/h0/out.
// ---------------------------------------------------------------------------
__global__ __launch_bounds__(512, 2) void gru_pipe(
    const float* x, const __bf16* __restrict__ frags,
    const float* __restrict__ b0, const float* __restrict__ b1,
    float* h0, float* out, int* flags)
{
    __shared__ __align__(16) __bf16 xb[2][2048];   // x_{t+2} tiles (ring of 2)
    __shared__ __align__(16) __bf16 hb[2][2048];   // h double buffer

    const int tid  = threadIdx.x;
    const int wave = tid >> 6, lane = tid & 63;
    const int l15  = lane & 15, quad = lane >> 4;
    const int pair  = blockIdx.x & 15;
    const int layer = blockIdx.x >> 4;
    const int B0 = pair * 16;
    int* const flagp = flags + pair * 16;          // one 64B line per pair

    const __bf16* Bf  = frags + (size_t)layer * 98304;
    const float* bias = layer ? b1 : b0;
    const float* xin  = layer ? h0 : x;
    float*       hout = layer ? out : h0;

    // persistent B-frags: W part (kt 0..3) and U part (kt 4..7), pinned so
    // the loads cannot be sunk into the t-loop (round-4 lesson).
    bf16x8 bw[3][4], bu[3][4];
#pragma unroll
    for (int g = 0; g < 3; g++) {
        int ct = 8 * g + wave;
#pragma unroll
        for (int kt = 0; kt < 4; kt++) {
            bw[g][kt] = *(const bf16x8*)(Bf + (size_t)((ct * 8 + kt) * 64 + lane) * 8);
            bu[g][kt] = *(const bf16x8*)(Bf + (size_t)((ct * 8 + kt + 4) * 64 + lane) * 8);
            __asm__ volatile("" : "+v"(bw[g][kt]));
            __asm__ volatile("" : "+v"(bu[g][kt]));
        }
    }

    const int j = wave * 16 + l15;
    const float bz  = (bias[j]       + bias[384 + j]) * L2E;
    const float br  = (bias[128 + j] + bias[512 + j]) * L2E;
    const float bxh = bias[256 + j] * L2E2;
    const float brh = bias[640 + j] * L2E2;

    // staging map: 512 threads cover 16 rows x 128 cols (4 floats each)
    const int srow = tid >> 5;
    const float* px = xin + (size_t)(B0 + srow) * 65536 + (tid & 31) * 4;
    // swizzled staging byte offset (8B store; XOR bits 4..6 stay row-local)
    const int sb = (srow * 256 + (tid & 31) * 8) ^ ((srow & 7) << 4);

    // A-frag byte offsets: row l15, k-cols quad*8 + kt*32 (bf16) -> bytes
    const int swz = (l15 & 7) << 4;
    const int abb = l15 * 256 + quad * 16;
    const int ao0 = (abb      ) ^ swz;
    const int ao1 = (abb +  64) ^ swz;
    const int ao2 = (abb + 128) ^ swz;
    const int ao3 = (abb + 192) ^ swz;
    // h-write byte offsets (scalar bf16, row = quad*4+r, col j)
    int hw_[4];
#pragma unroll
    for (int r = 0; r < 4; r++) {
        int row = quad * 4 + r;
        hw_[r] = (row * 256 + j * 2) ^ ((row & 7) << 4);
    }

    const size_t obase = (size_t)(B0 + quad * 4) * 65536 + j;

    int known = 0;
    if (layer) {                 // prologue + step 0..3 prefetch window
        while (known < 8) {
            __builtin_amdgcn_s_sleep(4);
            known = __hip_atomic_load(flagp, __ATOMIC_RELAXED,
                                      __HIP_MEMORY_SCOPE_AGENT);
        }
    }

#define LOADX(p) (layer ? __builtin_nontemporal_load((const f32x4*)(p)) \
                        : *(const f32x4*)(p))
#define PACKST(buf, v) do { bf16x4 hv_;                                  \
        hv_.x = (__bf16)(v)[0]; hv_.y = (__bf16)(v)[1];                  \
        hv_.z = (__bf16)(v)[2]; hv_.w = (__bf16)(v)[3];                  \
        *(bf16x4*)((char*)&(buf)[0] + sb) = hv_; } while (0)

    const f32x4 zv = {0.f, 0.f, 0.f, 0.f};

    // ---- prologue: stage x_0,x_1; zero h; compute xp_0, xp_1; stage x_2 ----
    {
        f32x4 v0 = LOADX(px);
        f32x4 v1 = LOADX(px + 128);
        PACKST(xb[0], v0);
        PACKST(xb[1], v1);
        ((uint64_t*)&hb[0][0])[tid] = 0ull;        // 4096 B = 512 x 8B
    }
    __syncthreads();

    f32x4 xpzE = zv, xprE = zv, xphE = zv;         // xp_0 (even set)
    f32x4 xpzO = zv, xprO = zv, xphO = zv;         // xp_1 (odd set)
    {
        bf16x8 Ax0 = *(const bf16x8*)((const char*)&xb[0][0] + ao0);
        bf16x8 Ax1 = *(const bf16x8*)((const char*)&xb[0][0] + ao1);
        bf16x8 Ax2 = *(const bf16x8*)((const char*)&xb[0][0] + ao2);
        bf16x8 Ax3 = *(const bf16x8*)((const char*)&xb[0][0] + ao3);
        xpzE = MFMA16(Ax0, bw[0][0], xpzE); xprE = MFMA16(Ax0, bw[1][0], xprE); xphE = MFMA16(Ax0, bw[2][0], xphE);
        xpzE = MFMA16(Ax1, bw[0][1], xpzE); xprE = MFMA16(Ax1, bw[1][1], xprE); xphE = MFMA16(Ax1, bw[2][1], xphE);
        xpzE = MFMA16(Ax2, bw[0][2], xpzE); xprE = MFMA16(Ax2, bw[1][2], xprE); xphE = MFMA16(Ax2, bw[2][2], xphE);
        xpzE = MFMA16(Ax3, bw[0][3], xpzE); xprE = MFMA16(Ax3, bw[1][3], xprE); xphE = MFMA16(Ax3, bw[2][3], xphE);
    }
    {
        bf16x8 Ax0 = *(const bf16x8*)((const char*)&xb[1][0] + ao0);
        bf16x8 Ax1 = *(const bf16x8*)((const char*)&xb[1][0] + ao1);
        bf16x8 Ax2 = *(const bf16x8*)((const char*)&xb[1][0] + ao2);
        bf16x8 Ax3 = *(const bf16x8*)((const char*)&xb[1][0] + ao3);
        xpzO = MFMA16(Ax0, bw[0][0], xpzO); xprO = MFMA16(Ax0, bw[1][0], xprO); xphO = MFMA16(Ax0, bw[2][0], xphO);
        xpzO = MFMA16(Ax1, bw[0][1], xpzO); xprO = MFMA16(Ax1, bw[1][1], xprO); xphO = MFMA16(Ax1, bw[2][1], xphO);
        xpzO = MFMA16(Ax2, bw[0][2], xpzO); xprO = MFMA16(Ax2, bw[1][2], xprO); xphO = MFMA16(Ax2, bw[2][2], xphO);
        xpzO = MFMA16(Ax3, bw[0][3], xpzO); xprO = MFMA16(Ax3, bw[1][3], xprO); xphO = MFMA16(Ax3, bw[2][3], xphO);
    }
    __syncthreads();                                // all reads of xb[0] done
    {
        f32x4 v2 = LOADX(px + 256);                 // x_2 -> slot 0
        PACKST(xb[0], v2);
    }
    f32x4 vc = LOADX(px + 384);                     // x_3 (staged at t=0)
    float hold[4] = {0.f, 0.f, 0.f, 0.f};
    __syncthreads();

    // Loop invariant at step t: hb[t&1] = h_{t-1}; xb[t&1] = x_{t+2};
    // xp carry (parity set) = xp_t; vc = x_{t+3}.
#define GRU_BODY(T, S, xpz, xpr, xph)                                         \
    {                                                                         \
        const int t_ = (T);                                                   \
        if (layer && ((t_ & 3) == 0)) {             /* decimated flag poll */ \
            int need = t_ + 8; if (need > 512) need = 512;                    \
            while (known < need) {                                            \
                __builtin_amdgcn_s_sleep(4);                                  \
                known = __hip_atomic_load(flagp, __ATOMIC_RELAXED,            \
                                          __HIP_MEMORY_SCOPE_AGENT);          \
            }                                                                 \
        }                                                                     \
        int t4_ = t_ + 4; if (t4_ > 511) t4_ = 511;                           \
        f32x4 vn = LOADX(px + (size_t)t4_ * 128);                             \
        bf16x8 Ah0 = *(const bf16x8*)((const char*)&hb[S][0] + ao0);          \
        bf16x8 Ah1 = *(const bf16x8*)((const char*)&hb[S][0] + ao1);          \
        bf16x8 Ah2 = *(const bf16x8*)((const char*)&hb[S][0] + ao2);          \
        bf16x8 Ah3 = *(const bf16x8*)((const char*)&hb[S][0] + ao3);          \
        bf16x8 Ax0 = *(const bf16x8*)((const char*)&xb[S][0] + ao0);          \
        bf16x8 Ax1 = *(const bf16x8*)((const char*)&xb[S][0] + ao1);          \
        bf16x8 Ax2 = *(const bf16x8*)((const char*)&xb[S][0] + ao2);          \
        bf16x8 Ax3 = *(const bf16x8*)((const char*)&xb[S][0] + ao3);          \
        f32x4 az = xpz, ar = xpr, ahh = zv;                                   \
        __builtin_amdgcn_s_setprio(1);                                        \
        az = MFMA16(Ah0, bu[0][0], az); ar = MFMA16(Ah0, bu[1][0], ar);       \
        ahh = MFMA16(Ah0, bu[2][0], ahh);                                     \
        az = MFMA16(Ah1, bu[0][1], az); ar = MFMA16(Ah1, bu[1][1], ar);       \
        ahh = MFMA16(Ah1, bu[2][1], ahh);                                     \
        az = MFMA16(Ah2, bu[0][2], az); ar = MFMA16(Ah2, bu[1][2], ar);       \
        ahh = MFMA16(Ah2, bu[2][2], ahh);                                     \
        az = MFMA16(Ah3, bu[0][3], az); ar = MFMA16(Ah3, bu[1][3], ar);       \
        ahh = MFMA16(Ah3, bu[2][3], ahh);                                     \
        /* independent: xp_{t+2} = x_{t+2}*W (drains under the epilogue) */   \
        f32x4 xhc = xph;                          /* xp_t h-part for epi */   \
        xpz = MFMA16(Ax0, bw[0][0], zv);                                      \
        xpr = MFMA16(Ax0, bw[1][0], zv);                                      \
        xph = MFMA16(Ax0, bw[2][0], zv);                                      \
        xpz = MFMA16(Ax1, bw[0][1], xpz); xpr = MFMA16(Ax1, bw[1][1], xpr);   \
        xph = MFMA16(Ax1, bw[2][1], xph);                                     \
        xpz = MFMA16(Ax2, bw[0][2], xpz); xpr = MFMA16(Ax2, bw[1][2], xpr);   \
        xph = MFMA16(Ax2, bw[2][2], xph);                                     \
        xpz = MFMA16(Ax3, bw[0][3], xpz); xpr = MFMA16(Ax3, bw[1][3], xpr);   \
        xph = MFMA16(Ax3, bw[2][3], xph);                                     \
        __builtin_amdgcn_s_setprio(0);                                        \
        /* epilogue (pre-scaled by log2e/2log2e -> raw 2^x) */                \
        float hnew[4];                                                        \
        _Pragma("unroll")                                                     \
        for (int r = 0; r < 4; r++) {                                         \
            float z  = __builtin_amdgcn_rcpf(                                 \
                           1.f + __builtin_amdgcn_exp2f(-(az[r] + bz)));      \
            float rg = __builtin_amdgcn_rcpf(                                 \
                           1.f + __builtin_amdgcn_exp2f(-(ar[r] + br)));      \
            float hp = (xhc[r] + bxh) + rg * (ahh[r] + brh);                  \
            float e2 = __builtin_amdgcn_exp2f(hp);                            \
            float th = 1.f - 2.f * __builtin_amdgcn_rcpf(e2 + 1.f);           \
            hnew[r] = th + z * (hold[r] - th);                                \
            hold[r] = hnew[r];                                                \
        }                                                                     \
        /* T19 ladder: ds_reads first, rec chain, then xp MFMAs threaded */   \
        /* through the epilogue VALU (forces MFMA||VALU overlap).         */  \
        __builtin_amdgcn_sched_group_barrier(0x100, 8, 0);   /* 8 DS_READ */  \
        __builtin_amdgcn_sched_group_barrier(0x008, 12, 0);  /* rec MFMAs */  \
        _Pragma("unroll")                                                     \
        for (int q_ = 0; q_ < 12; ++q_) {                                     \
            __builtin_amdgcn_sched_group_barrier(0x008, 1, 0); /* 1 xp MFMA */\
            __builtin_amdgcn_sched_group_barrier(0x002, 6, 0); /* 6 VALU   */ \
        }                                                                     \
        /* stage x_{t+3} and h_t into the opposite buffers */                 \
        PACKST(xb[(S) ^ 1], vc);                                              \
        _Pragma("unroll")                                                     \
        for (int r = 0; r < 4; r++)                                           \
            *(__bf16*)((char*)&hb[(S) ^ 1][0] + hw_[r]) = (__bf16)hnew[r];    \
        if (layer == 0 && (t_ & 3) == 3) {                                    \
            BAR_FULL();               /* h0 stores of steps <= t-1 in HBM */  \
            if (tid == 0)                                                     \
                __hip_atomic_store(flagp, t_, __ATOMIC_RELAXED,               \
                                   __HIP_MEMORY_SCOPE_AGENT);                 \
        } else {                                                              \
            BAR_LGKM();                                                       \
        }                                                                     \
        if (layer == 0) {                                                     \
            _Pragma("unroll")                                                 \
            for (int r = 0; r < 4; r++)                                       \
                __builtin_nontemporal_store(hnew[r],                          \
                    hout + obase + (size_t)r * 65536 + (size_t)t_ * 128);     \
        } else {                                                              \
            _Pragma("unroll")                                                 \
            for (int r = 0; r < 4; r++)                                       \
                hout[obase + (size_t)r * 65536 + (size_t)t_ * 128] = hnew[r]; \
        }                                                                     \
        vc = vn;                                                              \
    }

    for (int it = 0; it < 256; ++it) {
        GRU_BODY(2 * it,     0, xpzE, xprE, xphE);
        GRU_BODY(2 * it + 1, 1, xpzO, xprO, xphO);
    }
#undef GRU_BODY
#undef PACKST
#undef LOADX

    if (layer == 0) {
        BAR_FULL();        // drain final h0 stores (incl. step 511)
        if (tid == 0)
            __hip_atomic_store(flagp, 512, __ATOMIC_RELAXED,
                               __HIP_MEMORY_SCOPE_AGENT);
    }
}

// ---------------------------------------------------------------------------
extern "C" void kernel_launch(void* const* d_in, const int* in_sizes, int n_in,
                              void* d_out, int out_size, void* d_ws, size_t ws_size,
                              hipStream_t stream)
{
    const float* x  = (const float*)d_in[0];
    const float* W0 = (const float*)d_in[1];
    const float* U0 = (const float*)d_in[2];
    const float* b0 = (const float*)d_in[3];
    const float* W1 = (const float*)d_in[4];
    const float* U1 = (const float*)d_in[5];
    const float* b1 = (const float*)d_in[6];
    float* out = (float*)d_out;

    char* ws = (char*)d_ws;
    __bf16* frags = (__bf16*)ws;                 // 2 * 98304 bf16 = 393,216 B
    int*    flags = (int*)(ws + 393216);         // 16 pairs x 64 B = 1024 B
    // h0 at ws + 448 KiB if it fits, else alias d_out (pipeline-safe: consumer
    // reads slot t+4 strictly before overwriting slot t).
    float* h0;
    const size_t need = 458752 + 67108864;
    if (ws_size >= need) h0 = (float*)(ws + 458752);
    else                 h0 = out;

    prep_frags<<<48, 512, 0, stream>>>(W0, U0, W1, U1, frags, flags);
    gru_pipe<<<32, 512, 0, stream>>>(x, frags, b0, b1, h0, out, flags);
}